// Round 1
// baseline (668.828 us; speedup 1.0000x reference)
//
#include <hip/hip_runtime.h>
#include <hip/hip_bf16.h>
#include <math.h>

#define NEG_SLOPE 0.2f

// ---------------- init: zero deg + counter (ws is re-poisoned every launch) ----
__global__ void k_init(int* __restrict__ deg, int* __restrict__ counter, int N) {
    int i = blockIdx.x * blockDim.x + threadIdx.x;
    if (i < N) deg[i] = 0;
    if (i == 0) counter[0] = 0;
}

// ---------------- GEMM: h[N,128] = feat[N,256] @ W[128,256]^T ----------------
// block 128 threads, tile 64 nodes x 128 outs, BK=32, 8x8 microtile per thread
__global__ __launch_bounds__(128) void k_gemm(const float* __restrict__ feat,
                                              const float* __restrict__ W,
                                              float* __restrict__ h, int N) {
    __shared__ float featS[64][33];   // node-major, +1 pad: scalar reads conflict-free
    __shared__ float wT[32][132];     // k-major (transposed), row stride 132 (16B-aligned)
    const int t  = threadIdx.x;
    const int tx = t & 15;            // out group: outs 8*tx .. 8*tx+7
    const int ty = t >> 4;            // node group: nodes 8*ty .. 8*ty+7
    const int n0 = blockIdx.x * 64;

    float acc[8][8];
#pragma unroll
    for (int i = 0; i < 8; i++)
#pragma unroll
        for (int j = 0; j < 8; j++) acc[i][j] = 0.f;

    for (int k0 = 0; k0 < 256; k0 += 32) {
        // stage feat tile: 64 rows x 32 cols = 512 float4, 4 per thread
#pragma unroll
        for (int i = 0; i < 4; i++) {
            int f4 = t + i * 128;
            int row = f4 >> 3, c = f4 & 7;
            int n = n0 + row; if (n >= N) n = N - 1;   // clamp (stores are guarded)
            float4 v = *(const float4*)(feat + (size_t)n * 256 + k0 + c * 4);
            featS[row][c * 4 + 0] = v.x; featS[row][c * 4 + 1] = v.y;
            featS[row][c * 4 + 2] = v.z; featS[row][c * 4 + 3] = v.w;
        }
        // stage W tile transposed: 128 outs x 32 k = 1024 float4, 8 per thread
#pragma unroll
        for (int i = 0; i < 8; i++) {
            int f4 = t + i * 128;
            int row = f4 >> 3, c = f4 & 7;             // row = out index
            float4 v = *(const float4*)(W + (size_t)row * 256 + k0 + c * 4);
            wT[c * 4 + 0][row] = v.x; wT[c * 4 + 1][row] = v.y;
            wT[c * 4 + 2][row] = v.z; wT[c * 4 + 3][row] = v.w;
        }
        __syncthreads();
#pragma unroll
        for (int k = 0; k < 32; k++) {
            float a[8], b[8];
#pragma unroll
            for (int i = 0; i < 8; i++) a[i] = featS[ty * 8 + i][k];
            float4 b0 = *(const float4*)&wT[k][tx * 8];
            float4 b1 = *(const float4*)&wT[k][tx * 8 + 4];
            b[0] = b0.x; b[1] = b0.y; b[2] = b0.z; b[3] = b0.w;
            b[4] = b1.x; b[5] = b1.y; b[6] = b1.z; b[7] = b1.w;
#pragma unroll
            for (int i = 0; i < 8; i++)
#pragma unroll
                for (int j = 0; j < 8; j++) acc[i][j] += a[i] * b[j];
        }
        __syncthreads();
    }
#pragma unroll
    for (int i = 0; i < 8; i++) {
        int n = n0 + ty * 8 + i;
        if (n < N) {
            float4 o0 = {acc[i][0], acc[i][1], acc[i][2], acc[i][3]};
            float4 o1 = {acc[i][4], acc[i][5], acc[i][6], acc[i][7]};
            *(float4*)(h + (size_t)n * 128 + tx * 8)     = o0;
            *(float4*)(h + (size_t)n * 128 + tx * 8 + 4) = o1;
        }
    }
}

// ---------------- el/er: per-node head-wise dot with attn vectors ------------
__global__ void k_eler(const float* __restrict__ h, const float* __restrict__ al,
                       const float* __restrict__ ar, float* __restrict__ el,
                       float* __restrict__ er, int N) {
    int wid  = (blockIdx.x * blockDim.x + threadIdx.x) >> 6;
    int lane = threadIdx.x & 63;
    if (wid >= N) return;
    const float* hr = h + (size_t)wid * 128;
    float v0 = hr[lane], v1 = hr[lane + 64];
    float pl0 = v0 * al[lane], pl1 = v1 * al[lane + 64];
    float pr0 = v0 * ar[lane], pr1 = v1 * ar[lane + 64];
#pragma unroll
    for (int o = 1; o < 32; o <<= 1) {
        pl0 += __shfl_xor(pl0, o); pl1 += __shfl_xor(pl1, o);
        pr0 += __shfl_xor(pr0, o); pr1 += __shfl_xor(pr1, o);
    }
    if ((lane & 31) == 0) {
        int hh = lane >> 5;                       // 0 or 1
        el[wid * 4 + hh]     = pl0; el[wid * 4 + hh + 2] = pl1;
        er[wid * 4 + hh]     = pr0; er[wid * 4 + hh + 2] = pr1;
    }
}

// ---------------- per-edge pre-softmax score e_buf[E,4] ----------------------
__global__ void k_edge_e(const int* __restrict__ src, const int* __restrict__ dst,
                         const float* __restrict__ el, const float* __restrict__ er,
                         float* __restrict__ e_buf, int E4) {
    int g = blockIdx.x * blockDim.x + threadIdx.x;
    if (g >= E4) return;
    int e = g >> 2, hh = g & 3;
    float x = el[src[e] * 4 + hh] + er[dst[e] * 4 + hh];
    e_buf[g] = x > 0.f ? x : NEG_SLOPE * x;
}

// ---------------- CSR build: count / assign ranges / scatter -----------------
__global__ void k_count(const int* __restrict__ dst, int* __restrict__ deg, int E) {
    int g = blockIdx.x * blockDim.x + threadIdx.x;
    if (g < E) atomicAdd(&deg[dst[g]], 1);
}

__global__ void k_assign(const int* __restrict__ deg, int* __restrict__ start,
                         int* __restrict__ cursor, int* __restrict__ counter, int N) {
    int g = blockIdx.x * blockDim.x + threadIdx.x;
    int lane = threadIdx.x & 63;
    int d = (g < N) ? deg[g] : 0;
    int incl = d;
#pragma unroll
    for (int o = 1; o < 64; o <<= 1) {
        int y = __shfl_up(incl, o);
        if (lane >= o) incl += y;
    }
    int excl  = incl - d;
    int total = __shfl(incl, 63);
    int base  = 0;
    if (lane == 0) base = atomicAdd(counter, total);
    base = __shfl(base, 0);
    if (g < N) { start[g] = base + excl; cursor[g] = base + excl; }
}

__global__ void k_scatter(const int* __restrict__ dst, int* __restrict__ cursor,
                          int* __restrict__ edge_ids, int E) {
    int g = blockIdx.x * blockDim.x + threadIdx.x;
    if (g < E) {
        int p = atomicAdd(&cursor[dst[g]], 1);
        edge_ids[p] = g;
    }
}

// ---------------- gather-side aggregation: one wave per dst node -------------
// out[n] = bias + h[n]*sum_e h[src_e] + (sum_e ex_e h[src_e]) / denom
__global__ void k_agg(const float* __restrict__ h, const float* __restrict__ e_buf,
                      const int* __restrict__ src, const int* __restrict__ start,
                      const int* __restrict__ deg, const int* __restrict__ edge_ids,
                      const float* __restrict__ bias, float* __restrict__ out, int N) {
    int wid  = (blockIdx.x * blockDim.x + threadIdx.x) >> 6;
    int lane = threadIdx.x & 63;
    if (wid >= N) return;
    int h0  = lane >> 5;                 // head of element `lane` (0/1); +2 for lane+64
    int beg = start[wid], dg = deg[wid];

    float m0 = -INFINITY, m1 = -INFINITY;
    for (int i = 0; i < dg; i++) {
        int eid = edge_ids[beg + i];
        m0 = fmaxf(m0, e_buf[eid * 4 + h0]);
        m1 = fmaxf(m1, e_buf[eid * 4 + h0 + 2]);
    }
    float S10 = 0.f, S20 = 0.f, S11 = 0.f, S21 = 0.f, d0 = 0.f, d1 = 0.f;
    for (int i = 0; i < dg; i++) {
        int eid = edge_ids[beg + i];
        int s   = src[eid];
        const float* hs = h + (size_t)s * 128;
        float hv0 = hs[lane], hv1 = hs[lane + 64];
        float ex0 = __expf(e_buf[eid * 4 + h0]     - m0);
        float ex1 = __expf(e_buf[eid * 4 + h0 + 2] - m1);
        S10 += hv0; S20 += ex0 * hv0;
        S11 += hv1; S21 += ex1 * hv1;
        d0  += ex0; d1  += ex1;
    }
    const float* hn = h + (size_t)wid * 128;
    float o0 = bias[lane]      + hn[lane]      * S10 + (d0 > 0.f ? S20 / d0 : 0.f);
    float o1 = bias[lane + 64] + hn[lane + 64] * S11 + (d1 > 0.f ? S21 / d1 : 0.f);
    out[(size_t)wid * 128 + lane]      = o0;
    out[(size_t)wid * 128 + lane + 64] = o1;
}

extern "C" void kernel_launch(void* const* d_in, const int* in_sizes, int n_in,
                              void* d_out, int out_size, void* d_ws, size_t ws_size,
                              hipStream_t stream) {
    const float* feat = (const float*)d_in[0];
    const float* W_fc = (const float*)d_in[1];
    const float* al   = (const float*)d_in[2];
    const float* ar   = (const float*)d_in[3];
    const float* bias = (const float*)d_in[4];
    const int*   src  = (const int*)d_in[5];
    const int*   dst  = (const int*)d_in[6];
    const int N = in_sizes[0] / 256;
    const int E = in_sizes[5];

    char* ws = (char*)d_ws;
    size_t off = 0;
    float* h      = (float*)(ws + off); off += (size_t)N * 128 * 4;   // 51.2 MB
    float* el     = (float*)(ws + off); off += (size_t)N * 4 * 4;     // 1.6 MB
    float* er     = (float*)(ws + off); off += (size_t)N * 4 * 4;     // 1.6 MB
    float* e_buf  = (float*)(ws + off); off += (size_t)E * 4 * 4;     // 16 MB
    int* deg      = (int*)(ws + off);   off += (size_t)N * 4;         // 0.4 MB
    int* startA   = (int*)(ws + off);   off += (size_t)N * 4;
    int* cursor   = (int*)(ws + off);   off += (size_t)N * 4;
    int* edge_ids = (int*)(ws + off);   off += (size_t)E * 4;         // 4 MB
    int* counter  = (int*)(ws + off);   off += 256;

    float* out = (float*)d_out;

    k_init<<<(N + 255) / 256, 256, 0, stream>>>(deg, counter, N);
    k_gemm<<<(N + 63) / 64, 128, 0, stream>>>(feat, W_fc, h, N);
    k_eler<<<(N + 3) / 4, 256, 0, stream>>>(h, al, ar, el, er, N);
    k_edge_e<<<((E * 4) + 255) / 256, 256, 0, stream>>>(src, dst, el, er, e_buf, E * 4);
    k_count<<<(E + 255) / 256, 256, 0, stream>>>(dst, deg, E);
    k_assign<<<(N + 255) / 256, 256, 0, stream>>>(deg, startA, cursor, counter, N);
    k_scatter<<<(E + 255) / 256, 256, 0, stream>>>(dst, cursor, edge_ids, E);
    k_agg<<<(N + 3) / 4, 256, 0, stream>>>(h, e_buf, src, startA, deg, edge_ids,
                                           bias, out, N);
}

// Round 2
// 439.160 us; speedup vs baseline: 1.5230x; 1.5230x over previous
//
#include <hip/hip_runtime.h>
#include <hip/hip_bf16.h>
#include <math.h>

#define NEG_SLOPE 0.2f

__device__ __forceinline__ float uas(unsigned int u) { return __uint_as_float(u); }

// pick head's exp value from float4 (head = 0..3)
__device__ __forceinline__ float pick_h(const float4& e, int head) {
    float lo = (head & 1) ? e.y : e.x;
    float hi = (head & 1) ? e.w : e.z;
    return (head & 2) ? hi : lo;
}

// ---------------- init: zero deg + counter ----------------------------------
__global__ void k_init(int* __restrict__ deg, int* __restrict__ counter, int N) {
    int i = blockIdx.x * blockDim.x + threadIdx.x;
    if (i < N) deg[i] = 0;
    if (i == 0) counter[0] = 0;
}

// ---------------- GEMM: h[N,128] = feat[N,256] @ W[128,256]^T ----------------
__global__ __launch_bounds__(128) void k_gemm(const float* __restrict__ feat,
                                              const float* __restrict__ W,
                                              float* __restrict__ h, int N) {
    __shared__ float featS[64][33];
    __shared__ float wT[32][132];
    const int t  = threadIdx.x;
    const int tx = t & 15;
    const int ty = t >> 4;
    const int n0 = blockIdx.x * 64;

    float acc[8][8];
#pragma unroll
    for (int i = 0; i < 8; i++)
#pragma unroll
        for (int j = 0; j < 8; j++) acc[i][j] = 0.f;

    for (int k0 = 0; k0 < 256; k0 += 32) {
#pragma unroll
        for (int i = 0; i < 4; i++) {
            int f4 = t + i * 128;
            int row = f4 >> 3, c = f4 & 7;
            int n = n0 + row; if (n >= N) n = N - 1;
            float4 v = *(const float4*)(feat + (size_t)n * 256 + k0 + c * 4);
            featS[row][c * 4 + 0] = v.x; featS[row][c * 4 + 1] = v.y;
            featS[row][c * 4 + 2] = v.z; featS[row][c * 4 + 3] = v.w;
        }
#pragma unroll
        for (int i = 0; i < 8; i++) {
            int f4 = t + i * 128;
            int row = f4 >> 3, c = f4 & 7;
            float4 v = *(const float4*)(W + (size_t)row * 256 + k0 + c * 4);
            wT[c * 4 + 0][row] = v.x; wT[c * 4 + 1][row] = v.y;
            wT[c * 4 + 2][row] = v.z; wT[c * 4 + 3][row] = v.w;
        }
        __syncthreads();
#pragma unroll
        for (int k = 0; k < 32; k++) {
            float a[8], b[8];
#pragma unroll
            for (int i = 0; i < 8; i++) a[i] = featS[ty * 8 + i][k];
            float4 b0 = *(const float4*)&wT[k][tx * 8];
            float4 b1 = *(const float4*)&wT[k][tx * 8 + 4];
            b[0] = b0.x; b[1] = b0.y; b[2] = b0.z; b[3] = b0.w;
            b[4] = b1.x; b[5] = b1.y; b[6] = b1.z; b[7] = b1.w;
#pragma unroll
            for (int i = 0; i < 8; i++)
#pragma unroll
                for (int j = 0; j < 8; j++) acc[i][j] += a[i] * b[j];
        }
        __syncthreads();
    }
#pragma unroll
    for (int i = 0; i < 8; i++) {
        int n = n0 + ty * 8 + i;
        if (n < N) {
            float4 o0 = {acc[i][0], acc[i][1], acc[i][2], acc[i][3]};
            float4 o1 = {acc[i][4], acc[i][5], acc[i][6], acc[i][7]};
            *(float4*)(h + (size_t)n * 128 + tx * 8)     = o0;
            *(float4*)(h + (size_t)n * 128 + tx * 8 + 4) = o1;
        }
    }
}

// ---------------- el/er + bf16 shadow copy of h ------------------------------
// one wave per node; lane covers elements (2*lane, 2*lane+1) -> head = lane>>4
__global__ void k_eler(const float* __restrict__ h, const float* __restrict__ al,
                       const float* __restrict__ ar, float* __restrict__ el,
                       float* __restrict__ er, unsigned int* __restrict__ hbu, int N) {
    int wid  = (blockIdx.x * blockDim.x + threadIdx.x) >> 6;
    int lane = threadIdx.x & 63;
    if (wid >= N) return;
    float2 v   = ((const float2*)(h + (size_t)wid * 128))[lane];
    float2 a2l = ((const float2*)al)[lane];
    float2 a2r = ((const float2*)ar)[lane];

    // bf16 pack (round-to-nearest)
    __hip_bfloat16 bx = __float2bfloat16(v.x);
    __hip_bfloat16 by = __float2bfloat16(v.y);
    unsigned int ux = *(unsigned short*)&bx;
    unsigned int uy = *(unsigned short*)&by;
    hbu[(size_t)wid * 64 + lane] = ux | (uy << 16);

    float pl = v.x * a2l.x + v.y * a2l.y;
    float pr = v.x * a2r.x + v.y * a2r.y;
#pragma unroll
    for (int o = 1; o < 16; o <<= 1) {
        pl += __shfl_xor(pl, o);
        pr += __shfl_xor(pr, o);
    }
    if ((lane & 15) == 0) {
        int hh = lane >> 4;
        el[wid * 4 + hh] = pl;
        er[wid * 4 + hh] = pr;
    }
}

// ---------------- CSR build: count / assign ----------------------------------
__global__ void k_count(const int* __restrict__ dst, int* __restrict__ deg, int E) {
    int g = blockIdx.x * blockDim.x + threadIdx.x;
    if (g < E) atomicAdd(&deg[dst[g]], 1);
}

__global__ void k_assign(const int* __restrict__ deg, int* __restrict__ start,
                         int* __restrict__ cursor, int* __restrict__ counter, int N) {
    int g = blockIdx.x * blockDim.x + threadIdx.x;
    int lane = threadIdx.x & 63;
    int d = (g < N) ? deg[g] : 0;
    int incl = d;
#pragma unroll
    for (int o = 1; o < 64; o <<= 1) {
        int y = __shfl_up(incl, o);
        if (lane >= o) incl += y;
    }
    int excl  = incl - d;
    int total = __shfl(incl, 63);
    int base  = 0;
    if (lane == 0) base = atomicAdd(counter, total);
    base = __shfl(base, 0);
    if (g < N) { start[g] = base + excl; cursor[g] = base + excl; }
}

// ---------------- scatter + score: CSR payload (src, exp(leaky(score))) ------
// NOTE: no segment-max subtraction — scores are small (|el|,|er| ~< 4), exp is
// safe in fp32, and the softmax ratio is mathematically unchanged.
__global__ void k_scatter(const int* __restrict__ src, const int* __restrict__ dst,
                          const float* __restrict__ el, const float* __restrict__ er,
                          int* __restrict__ cursor, int* __restrict__ src_csr,
                          float4* __restrict__ ex_csr, int E) {
    int g = blockIdx.x * blockDim.x + threadIdx.x;
    if (g >= E) return;
    int s = src[g], d = dst[g];
    int p = atomicAdd(&cursor[d], 1);
    float4 l = *(const float4*)(el + (size_t)s * 4);
    float4 r = *(const float4*)(er + (size_t)d * 4);
    float4 x;
    float t0 = l.x + r.x, t1 = l.y + r.y, t2 = l.z + r.z, t3 = l.w + r.w;
    t0 = t0 > 0.f ? t0 : NEG_SLOPE * t0;
    t1 = t1 > 0.f ? t1 : NEG_SLOPE * t1;
    t2 = t2 > 0.f ? t2 : NEG_SLOPE * t2;
    t3 = t3 > 0.f ? t3 : NEG_SLOPE * t3;
    x.x = __expf(t0); x.y = __expf(t1); x.z = __expf(t2); x.w = __expf(t3);
    src_csr[p] = s;
    ex_csr[p]  = x;
}

// ---------------- gather-side aggregation: one wave per dst node -------------
// out[n] = bias + h[n]*sum_e hb[src_e] + (sum_e ex_e hb[src_e]) / sum_e ex_e
__global__ __launch_bounds__(256) void k_agg(
        const unsigned int* __restrict__ hbu, const float* __restrict__ h,
        const float4* __restrict__ ex_csr, const int* __restrict__ src_csr,
        const int* __restrict__ start, const int* __restrict__ deg,
        const float* __restrict__ bias, float* __restrict__ out, int N) {
    int wid  = blockIdx.x * 4 + (threadIdx.x >> 6);
    int lane = threadIdx.x & 63;
    if (wid >= N) return;
    int beg = __builtin_amdgcn_readfirstlane(start[wid]);
    int dg  = __builtin_amdgcn_readfirstlane(deg[wid]);
    int head = lane >> 4;   // elements (2*lane, 2*lane+1) share one head

    float S1x = 0.f, S1y = 0.f, S2x = 0.f, S2y = 0.f, dd = 0.f;
    int i = 0;
    for (; i + 4 <= dg; i += 4) {
        int b = beg + i;
        int s0 = src_csr[b], s1 = src_csr[b + 1], s2 = src_csr[b + 2], s3 = src_csr[b + 3];
        float4 e0 = ex_csr[b], e1 = ex_csr[b + 1], e2 = ex_csr[b + 2], e3 = ex_csr[b + 3];
        unsigned int u0 = hbu[(size_t)s0 * 64 + lane];
        unsigned int u1 = hbu[(size_t)s1 * 64 + lane];
        unsigned int u2 = hbu[(size_t)s2 * 64 + lane];
        unsigned int u3 = hbu[(size_t)s3 * 64 + lane];
        float x0 = uas(u0 << 16), y0 = uas(u0 & 0xFFFF0000u);
        float x1 = uas(u1 << 16), y1 = uas(u1 & 0xFFFF0000u);
        float x2 = uas(u2 << 16), y2 = uas(u2 & 0xFFFF0000u);
        float x3 = uas(u3 << 16), y3 = uas(u3 & 0xFFFF0000u);
        float w0 = pick_h(e0, head), w1 = pick_h(e1, head);
        float w2 = pick_h(e2, head), w3 = pick_h(e3, head);
        S1x += (x0 + x1) + (x2 + x3);
        S1y += (y0 + y1) + (y2 + y3);
        S2x += w0 * x0 + w1 * x1 + w2 * x2 + w3 * x3;
        S2y += w0 * y0 + w1 * y1 + w2 * y2 + w3 * y3;
        dd  += (w0 + w1) + (w2 + w3);
    }
    for (; i < dg; i++) {
        int b = beg + i;
        int s0 = src_csr[b];
        float4 e0 = ex_csr[b];
        unsigned int u0 = hbu[(size_t)s0 * 64 + lane];
        float x0 = uas(u0 << 16), y0 = uas(u0 & 0xFFFF0000u);
        float w0 = pick_h(e0, head);
        S1x += x0; S1y += y0;
        S2x += w0 * x0; S2y += w0 * y0;
        dd  += w0;
    }

    float2 hv = ((const float2*)(h + (size_t)wid * 128))[lane];
    float2 bv = ((const float2*)bias)[lane];
    float inv = dd > 0.f ? 1.f / dd : 0.f;
    float ox = bv.x + hv.x * S1x + S2x * inv;
    float oy = bv.y + hv.y * S1y + S2y * inv;
    float2 o = {ox, oy};
    ((float2*)(out + (size_t)wid * 128))[lane] = o;
}

extern "C" void kernel_launch(void* const* d_in, const int* in_sizes, int n_in,
                              void* d_out, int out_size, void* d_ws, size_t ws_size,
                              hipStream_t stream) {
    const float* feat = (const float*)d_in[0];
    const float* W_fc = (const float*)d_in[1];
    const float* al   = (const float*)d_in[2];
    const float* ar   = (const float*)d_in[3];
    const float* bias = (const float*)d_in[4];
    const int*   src  = (const int*)d_in[5];
    const int*   dst  = (const int*)d_in[6];
    const int N = in_sizes[0] / 256;
    const int E = in_sizes[5];

    char* ws = (char*)d_ws;
    size_t off = 0;
    float* h            = (float*)(ws + off); off += (size_t)N * 128 * 4;  // 51.2 MB
    unsigned int* hbu   = (unsigned int*)(ws + off); off += (size_t)N * 64 * 4; // 25.6 MB
    float* el           = (float*)(ws + off); off += (size_t)N * 4 * 4;    // 1.6 MB
    float* er           = (float*)(ws + off); off += (size_t)N * 4 * 4;    // 1.6 MB
    int* deg            = (int*)(ws + off);   off += (size_t)N * 4;
    int* startA         = (int*)(ws + off);   off += (size_t)N * 4;
    int* cursor         = (int*)(ws + off);   off += (size_t)N * 4;
    int* src_csr        = (int*)(ws + off);   off += (size_t)E * 4;        // 4 MB
    float4* ex_csr      = (float4*)(ws + off); off += (size_t)E * 16;      // 16 MB
    int* counter        = (int*)(ws + off);   off += 256;

    float* out = (float*)d_out;

    k_init<<<(N + 255) / 256, 256, 0, stream>>>(deg, counter, N);
    k_gemm<<<(N + 63) / 64, 128, 0, stream>>>(feat, W_fc, h, N);
    k_eler<<<(N + 3) / 4, 256, 0, stream>>>(h, al, ar, el, er, hbu, N);
    k_count<<<(E + 255) / 256, 256, 0, stream>>>(dst, deg, E);
    k_assign<<<(N + 255) / 256, 256, 0, stream>>>(deg, startA, cursor, counter, N);
    k_scatter<<<(E + 255) / 256, 256, 0, stream>>>(src, dst, el, er, cursor,
                                                   src_csr, ex_csr, E);
    k_agg<<<(N + 3) / 4, 256, 0, stream>>>(hbu, h, ex_csr, src_csr, startA, deg,
                                           bias, out, N);
}

// Round 3
// 383.458 us; speedup vs baseline: 1.7442x; 1.1453x over previous
//
#include <hip/hip_runtime.h>
#include <hip/hip_bf16.h>
#include <math.h>

#define NEG_SLOPE 0.2f

typedef __attribute__((ext_vector_type(8))) short short8v;
typedef __attribute__((ext_vector_type(4))) float f32x4;

__device__ __forceinline__ float uas(unsigned int u) { return __uint_as_float(u); }

__device__ __forceinline__ unsigned short f2bf(float x) {
    __hip_bfloat16 b = __float2bfloat16(x);
    return *(unsigned short*)&b;
}

// pick head's exp value from float4 (head = 0..3)
__device__ __forceinline__ float pick_h(const float4& e, int head) {
    float lo = (head & 1) ? e.y : e.x;
    float hi = (head & 1) ? e.w : e.z;
    return (head & 2) ? hi : lo;
}

// ---------------- init: zero deg + counter ----------------------------------
__global__ void k_init(int* __restrict__ deg, int* __restrict__ counter, int N) {
    int i = blockIdx.x * blockDim.x + threadIdx.x;
    if (i < N) deg[i] = 0;
    if (i == 0) counter[0] = 0;
}

// ---------------- MFMA GEMM: hb[N,128](bf16) = bf16(feat[N,256]) @ bf16(W)^T --
// block = 256 thr (4 waves); tile 128 nodes x 128 outs; 16x16x32 bf16 MFMA.
// W is converted once per block into LDS in FRAGMENT order:
//   slot(kstep,ntile) at shorts[(kstep*8+ntile)*512], lane L holds
//   B[n=16*ntile+(L&15)][k=32*kstep+(L>>4)*8+j], j=0..7  -> lane-contiguous 16B.
__global__ __launch_bounds__(256) void k_gemm(const float* __restrict__ feat,
                                              const float* __restrict__ W,
                                              unsigned short* __restrict__ hb, int N) {
    __shared__ short wlds[32768];   // 64 KB
    const int t    = threadIdx.x;
    const int lane = t & 63;
    const int wave = t >> 6;
    const int n0   = blockIdx.x * 128;

    // ---- stage W (fp32 -> bf16, fragment order). 4096 slots of (n, kgroup).
#pragma unroll
    for (int i = 0; i < 16; i++) {
        int p  = t + i * 256;       // 0..4095
        int n  = p & 127;
        int kg = p >> 7;            // 0..31 (k-group of 8)
        const float* wp = W + (size_t)n * 256 + kg * 8;
        float4 v0 = *(const float4*)wp;
        float4 v1 = *(const float4*)(wp + 4);
        short s8[8];
        s8[0] = (short)f2bf(v0.x); s8[1] = (short)f2bf(v0.y);
        s8[2] = (short)f2bf(v0.z); s8[3] = (short)f2bf(v0.w);
        s8[4] = (short)f2bf(v1.x); s8[5] = (short)f2bf(v1.y);
        s8[6] = (short)f2bf(v1.z); s8[7] = (short)f2bf(v1.w);
        int kstep = kg >> 2, ntile = n >> 4;
        int L     = (kg & 3) * 16 + (n & 15);
        int slot  = kstep * 8 + ntile;
        *(short8v*)&wlds[(slot * 64 + L) * 8] = *(short8v*)s8;
    }
    __syncthreads();

    const int wm0 = wave * 32;      // wave's row offset inside the 128-row tile
    const int g   = lane >> 4;      // k-quad
    int row0 = n0 + wm0 + (lane & 15);
    int row1 = row0 + 16;
    int r0c = row0 < N ? row0 : N - 1;
    int r1c = row1 < N ? row1 : N - 1;

    f32x4 acc[2][8];
#pragma unroll
    for (int mt = 0; mt < 2; mt++)
#pragma unroll
        for (int nt = 0; nt < 8; nt++) acc[mt][nt] = (f32x4){0.f, 0.f, 0.f, 0.f};

#pragma unroll
    for (int ks = 0; ks < 8; ks++) {
        short8v afrag[2];
#pragma unroll
        for (int mt = 0; mt < 2; mt++) {
            const float* ap = feat + (size_t)(mt ? r1c : r0c) * 256 + ks * 32 + g * 8;
            float4 v0 = *(const float4*)ap;
            float4 v1 = *(const float4*)(ap + 4);
            short s8[8];
            s8[0] = (short)f2bf(v0.x); s8[1] = (short)f2bf(v0.y);
            s8[2] = (short)f2bf(v0.z); s8[3] = (short)f2bf(v0.w);
            s8[4] = (short)f2bf(v1.x); s8[5] = (short)f2bf(v1.y);
            s8[6] = (short)f2bf(v1.z); s8[7] = (short)f2bf(v1.w);
            afrag[mt] = *(short8v*)s8;
        }
#pragma unroll
        for (int nt = 0; nt < 8; nt++) {
            short8v b = *(short8v*)&wlds[((ks * 8 + nt) * 64 + lane) * 8];
            acc[0][nt] = __builtin_amdgcn_mfma_f32_16x16x32_bf16(afrag[0], b, acc[0][nt], 0, 0, 0);
            acc[1][nt] = __builtin_amdgcn_mfma_f32_16x16x32_bf16(afrag[1], b, acc[1][nt], 0, 0, 0);
        }
    }

    // epilogue: C/D layout col=lane&15, row=(lane>>4)*4+reg
#pragma unroll
    for (int mt = 0; mt < 2; mt++)
#pragma unroll
        for (int r = 0; r < 4; r++) {
            int m = n0 + wm0 + mt * 16 + (lane >> 4) * 4 + r;
            if (m < N) {
#pragma unroll
                for (int nt = 0; nt < 8; nt++) {
                    float v = acc[mt][nt][r];
                    hb[(size_t)m * 128 + nt * 16 + (lane & 15)] = f2bf(v);
                }
            }
        }
}

// ---------------- el/er from bf16 h ------------------------------------------
// one wave per node; lane covers elements (2*lane, 2*lane+1) -> head = lane>>4
__global__ void k_eler(const unsigned int* __restrict__ hbu, const float* __restrict__ al,
                       const float* __restrict__ ar, float* __restrict__ el,
                       float* __restrict__ er, int N) {
    int wid  = (blockIdx.x * blockDim.x + threadIdx.x) >> 6;
    int lane = threadIdx.x & 63;
    if (wid >= N) return;
    unsigned int u = hbu[(size_t)wid * 64 + lane];
    float vx = uas(u << 16), vy = uas(u & 0xFFFF0000u);
    float2 a2l = ((const float2*)al)[lane];
    float2 a2r = ((const float2*)ar)[lane];
    float pl = vx * a2l.x + vy * a2l.y;
    float pr = vx * a2r.x + vy * a2r.y;
#pragma unroll
    for (int o = 1; o < 16; o <<= 1) {
        pl += __shfl_xor(pl, o);
        pr += __shfl_xor(pr, o);
    }
    if ((lane & 15) == 0) {
        int hh = lane >> 4;
        el[wid * 4 + hh] = pl;
        er[wid * 4 + hh] = pr;
    }
}

// ---------------- CSR build: count / assign ----------------------------------
__global__ void k_count(const int* __restrict__ dst, int* __restrict__ deg, int E) {
    int g = blockIdx.x * blockDim.x + threadIdx.x;
    if (g < E) atomicAdd(&deg[dst[g]], 1);
}

__global__ void k_assign(const int* __restrict__ deg, int* __restrict__ start,
                         int* __restrict__ cursor, int* __restrict__ counter, int N) {
    int g = blockIdx.x * blockDim.x + threadIdx.x;
    int lane = threadIdx.x & 63;
    int d = (g < N) ? deg[g] : 0;
    int incl = d;
#pragma unroll
    for (int o = 1; o < 64; o <<= 1) {
        int y = __shfl_up(incl, o);
        if (lane >= o) incl += y;
    }
    int excl  = incl - d;
    int total = __shfl(incl, 63);
    int base  = 0;
    if (lane == 0) base = atomicAdd(counter, total);
    base = __shfl(base, 0);
    if (g < N) { start[g] = base + excl; cursor[g] = base + excl; }
}

// ---------------- scatter + score: CSR payload (src, exp(leaky(score))) ------
// No segment-max subtraction: scores are O(few), exp safe in fp32, softmax
// ratio unchanged.
__global__ void k_scatter(const int* __restrict__ src, const int* __restrict__ dst,
                          const float* __restrict__ el, const float* __restrict__ er,
                          int* __restrict__ cursor, int* __restrict__ src_csr,
                          float4* __restrict__ ex_csr, int E) {
    int g = blockIdx.x * blockDim.x + threadIdx.x;
    if (g >= E) return;
    int s = src[g], d = dst[g];
    int p = atomicAdd(&cursor[d], 1);
    float4 l = *(const float4*)(el + (size_t)s * 4);
    float4 r = *(const float4*)(er + (size_t)d * 4);
    float4 x;
    float t0 = l.x + r.x, t1 = l.y + r.y, t2 = l.z + r.z, t3 = l.w + r.w;
    t0 = t0 > 0.f ? t0 : NEG_SLOPE * t0;
    t1 = t1 > 0.f ? t1 : NEG_SLOPE * t1;
    t2 = t2 > 0.f ? t2 : NEG_SLOPE * t2;
    t3 = t3 > 0.f ? t3 : NEG_SLOPE * t3;
    x.x = __expf(t0); x.y = __expf(t1); x.z = __expf(t2); x.w = __expf(t3);
    src_csr[p] = s;
    ex_csr[p]  = x;
}

// ---------------- gather-side aggregation: one wave per dst node -------------
// out[n] = bias + hb[n]*sum_e hb[src_e] + (sum_e ex_e hb[src_e]) / sum_e ex_e
__global__ __launch_bounds__(256) void k_agg(
        const unsigned int* __restrict__ hbu,
        const float4* __restrict__ ex_csr, const int* __restrict__ src_csr,
        const int* __restrict__ start, const int* __restrict__ deg,
        const float* __restrict__ bias, float* __restrict__ out, int N) {
    int wid  = blockIdx.x * 4 + (threadIdx.x >> 6);
    int lane = threadIdx.x & 63;
    if (wid >= N) return;
    int beg = __builtin_amdgcn_readfirstlane(start[wid]);
    int dg  = __builtin_amdgcn_readfirstlane(deg[wid]);
    int head = lane >> 4;   // elements (2*lane, 2*lane+1) share one head

    float S1x = 0.f, S1y = 0.f, S2x = 0.f, S2y = 0.f, dd = 0.f;
    int i = 0;
    for (; i + 4 <= dg; i += 4) {
        int b = beg + i;
        int s0 = src_csr[b], s1 = src_csr[b + 1], s2 = src_csr[b + 2], s3 = src_csr[b + 3];
        float4 e0 = ex_csr[b], e1 = ex_csr[b + 1], e2 = ex_csr[b + 2], e3 = ex_csr[b + 3];
        unsigned int u0 = hbu[(size_t)s0 * 64 + lane];
        unsigned int u1 = hbu[(size_t)s1 * 64 + lane];
        unsigned int u2 = hbu[(size_t)s2 * 64 + lane];
        unsigned int u3 = hbu[(size_t)s3 * 64 + lane];
        float x0 = uas(u0 << 16), y0 = uas(u0 & 0xFFFF0000u);
        float x1 = uas(u1 << 16), y1 = uas(u1 & 0xFFFF0000u);
        float x2 = uas(u2 << 16), y2 = uas(u2 & 0xFFFF0000u);
        float x3 = uas(u3 << 16), y3 = uas(u3 & 0xFFFF0000u);
        float w0 = pick_h(e0, head), w1 = pick_h(e1, head);
        float w2 = pick_h(e2, head), w3 = pick_h(e3, head);
        S1x += (x0 + x1) + (x2 + x3);
        S1y += (y0 + y1) + (y2 + y3);
        S2x += w0 * x0 + w1 * x1 + w2 * x2 + w3 * x3;
        S2y += w0 * y0 + w1 * y1 + w2 * y2 + w3 * y3;
        dd  += (w0 + w1) + (w2 + w3);
    }
    for (; i < dg; i++) {
        int b = beg + i;
        int s0 = src_csr[b];
        float4 e0 = ex_csr[b];
        unsigned int u0 = hbu[(size_t)s0 * 64 + lane];
        float x0 = uas(u0 << 16), y0 = uas(u0 & 0xFFFF0000u);
        float w0 = pick_h(e0, head);
        S1x += x0; S1y += y0;
        S2x += w0 * x0; S2y += w0 * y0;
        dd  += w0;
    }

    unsigned int uh = hbu[(size_t)wid * 64 + lane];
    float hvx = uas(uh << 16), hvy = uas(uh & 0xFFFF0000u);
    float2 bv = ((const float2*)bias)[lane];
    float inv = dd > 0.f ? 1.f / dd : 0.f;
    float ox = bv.x + hvx * S1x + S2x * inv;
    float oy = bv.y + hvy * S1y + S2y * inv;
    float2 o = {ox, oy};
    ((float2*)(out + (size_t)wid * 128))[lane] = o;
}

extern "C" void kernel_launch(void* const* d_in, const int* in_sizes, int n_in,
                              void* d_out, int out_size, void* d_ws, size_t ws_size,
                              hipStream_t stream) {
    const float* feat = (const float*)d_in[0];
    const float* W_fc = (const float*)d_in[1];
    const float* al   = (const float*)d_in[2];
    const float* ar   = (const float*)d_in[3];
    const float* bias = (const float*)d_in[4];
    const int*   src  = (const int*)d_in[5];
    const int*   dst  = (const int*)d_in[6];
    const int N = in_sizes[0] / 256;
    const int E = in_sizes[5];

    char* ws = (char*)d_ws;
    size_t off = 0;
    unsigned int* hbu   = (unsigned int*)(ws + off); off += (size_t)N * 64 * 4; // 25.6 MB
    float* el           = (float*)(ws + off); off += (size_t)N * 4 * 4;    // 1.6 MB
    float* er           = (float*)(ws + off); off += (size_t)N * 4 * 4;    // 1.6 MB
    int* deg            = (int*)(ws + off);   off += (size_t)N * 4;
    int* startA         = (int*)(ws + off);   off += (size_t)N * 4;
    int* cursor         = (int*)(ws + off);   off += (size_t)N * 4;
    int* src_csr        = (int*)(ws + off);   off += (size_t)E * 4;        // 4 MB
    float4* ex_csr      = (float4*)(ws + off); off += (size_t)E * 16;      // 16 MB
    int* counter        = (int*)(ws + off);   off += 256;

    float* out = (float*)d_out;

    k_init<<<(N + 255) / 256, 256, 0, stream>>>(deg, counter, N);
    k_gemm<<<(N + 127) / 128, 256, 0, stream>>>(feat, W_fc, (unsigned short*)hbu, N);
    k_eler<<<(N + 3) / 4, 256, 0, stream>>>(hbu, al, ar, el, er, N);
    k_count<<<(E + 255) / 256, 256, 0, stream>>>(dst, deg, E);
    k_assign<<<(N + 255) / 256, 256, 0, stream>>>(deg, startA, cursor, counter, N);
    k_scatter<<<(E + 255) / 256, 256, 0, stream>>>(src, dst, el, er, cursor,
                                                   src_csr, ex_csr, E);
    k_agg<<<(N + 3) / 4, 256, 0, stream>>>(hbu, ex_csr, src_csr, startA, deg,
                                           bias, out, N);
}